// Round 1
// baseline (182.531 us; speedup 1.0000x reference)
//
#include <hip/hip_runtime.h>
#include <math.h>

// Problem constants
#define BATCH 16
#define CIN 32
#define COUT 96
#define WH 64
#define IMG (WH*WH)            // 4096
#define NPIX (BATCH*IMG)       // 65536 per channel
#define YELEMS (BATCH*COUT*IMG) // 6291456

// conv: grid 768 = 16 b * 3 cfg * 4 chgroup * 4 rowgroup ; block 256
__global__ __launch_bounds__(256) void conv_stats_kernel(
    const float* __restrict__ x, const float* __restrict__ w,
    float* __restrict__ y, float* __restrict__ psum, float* __restrict__ psq)
{
    int bid  = blockIdx.x;
    int rowg = bid & 3;
    int chg  = (bid >> 2) & 3;
    int rest = bid >> 4;          // 0..47
    int cfg  = rest % 3;
    int b    = rest / 3;
    int d    = cfg + 1;           // dilation 1,2,3
    int ocb  = cfg * 32 + chg * 8; // global out-channel base
    int i0   = rowg * 16;

    int t    = threadIdx.x;
    int j    = t & 63;            // column
    int li0  = (t >> 6) * 4;      // local row base (0,4,8,12)

    __shared__ float xs[22][64];  // halo rows i0-3 .. i0+18 (covers d<=3)
    __shared__ float wl[8][9];
    __shared__ float red[4][16];

    float acc[4][8];
#pragma unroll
    for (int r = 0; r < 4; r++)
#pragma unroll
        for (int o = 0; o < 8; o++) acc[r][o] = 0.f;

    const float* xb = x + (size_t)b * CIN * IMG;

    for (int c = 0; c < CIN; c++) {
        const float* xc = xb + c * IMG;
        // stage 22 rows x 64 cols, float4 per load: 352 float4s
        for (int idx = t; idx < 22 * 16; idx += 256) {
            int rr = idx >> 4;
            int cc = (idx & 15) * 4;
            int gi = (i0 - 3 + rr) & 63;
            *(float4*)(&xs[rr][cc]) = *(const float4*)(xc + gi * 64 + cc);
        }
        // stage 8ch x 9 taps of weights (block-uniform)
        if (t < 72) {
            int o = t / 9, tap = t % 9;
            int du = tap / 3, dv = tap % 3;
            wl[o][tap] = w[(((size_t)(ocb + o) * CIN + c) * 65 + (32 + (du - 1) * d)) * 65
                           + (32 + (dv - 1) * d)];
        }
        __syncthreads();

#pragma unroll
        for (int du = 0; du < 3; du++) {
            float xr[4][3];
            int lrb = li0 + 3 + (du - 1) * d;
#pragma unroll
            for (int r = 0; r < 4; r++) {
                int lr = lrb + r;
                xr[r][0] = xs[lr][(j - d) & 63];
                xr[r][1] = xs[lr][j];
                xr[r][2] = xs[lr][(j + d) & 63];
            }
#pragma unroll
            for (int o = 0; o < 8; o++) {
#pragma unroll
                for (int dv = 0; dv < 3; dv++) {
                    float wv = wl[o][du * 3 + dv];
#pragma unroll
                    for (int r = 0; r < 4; r++)
                        acc[r][o] = fmaf(xr[r][dv], wv, acc[r][o]);
                }
            }
        }
        __syncthreads();
    }

    // write y (coalesced over j) + per-thread sum/sumsq per channel
    float s[8], q[8];
#pragma unroll
    for (int o = 0; o < 8; o++) { s[o] = 0.f; q[o] = 0.f; }
#pragma unroll
    for (int o = 0; o < 8; o++) {
        size_t base = (((size_t)b * COUT + (ocb + o)) * WH) * WH;
#pragma unroll
        for (int r = 0; r < 4; r++) {
            float v = acc[r][o];
            y[base + (size_t)(i0 + li0 + r) * WH + j] = v;
            s[o] += v;
            q[o] = fmaf(v, v, q[o]);
        }
    }

    // wave butterfly reduce (64 lanes)
#pragma unroll
    for (int o = 0; o < 8; o++) {
        for (int m = 1; m < 64; m <<= 1) {
            s[o] += __shfl_xor(s[o], m, 64);
            q[o] += __shfl_xor(q[o], m, 64);
        }
    }
    int wv = t >> 6, lane = t & 63;
    if (lane == 0) {
#pragma unroll
        for (int o = 0; o < 8; o++) { red[wv][o] = s[o]; red[wv][8 + o] = q[o]; }
    }
    __syncthreads();
    if (t < 16) {
        float v = red[0][t] + red[1][t] + red[2][t] + red[3][t];
        int o = t & 7;
        int slot = (ocb + o) * 64 + b * 4 + rowg;  // 64 partials per channel
        if (t < 8) psum[slot] = v; else psq[slot] = v;
    }
}

__global__ __launch_bounds__(128) void finalize_kernel(
    const float* __restrict__ psum, const float* __restrict__ psq,
    const float* __restrict__ gamma, const float* __restrict__ beta,
    float* __restrict__ scale, float* __restrict__ shift)
{
    int ch = threadIdx.x;
    if (ch >= COUT) return;
    float s = 0.f, q = 0.f;
    for (int k = 0; k < 64; k++) { s += psum[ch * 64 + k]; q += psq[ch * 64 + k]; }
    float inv_n = 1.0f / (float)NPIX;
    float mean = s * inv_n;
    float var  = q * inv_n - mean * mean;
    float inv  = rsqrtf(var + 1e-5f);
    float a    = gamma[ch] * inv;
    scale[ch]  = a;
    shift[ch]  = beta[ch] - mean * a;
}

// 6144 blocks * 256 threads * 1 float4 each = 6291456 elems
__global__ __launch_bounds__(256) void bn_tanh_kernel(
    const float* __restrict__ y, const float* __restrict__ scale,
    const float* __restrict__ shift, float* __restrict__ out)
{
    size_t e4 = (size_t)blockIdx.x * 256 + threadIdx.x;
    int ch = (int)((e4 >> 10) % COUT);   // e4*4/4096 % 96
    float a = scale[ch], bsh = shift[ch];
    float4 v = ((const float4*)y)[e4];
    float4 r;
    r.x = tanhf(fmaf(v.x, a, bsh));
    r.y = tanhf(fmaf(v.y, a, bsh));
    r.z = tanhf(fmaf(v.z, a, bsh));
    r.w = tanhf(fmaf(v.w, a, bsh));
    ((float4*)out)[e4] = r;
}

extern "C" void kernel_launch(void* const* d_in, const int* in_sizes, int n_in,
                              void* d_out, int out_size, void* d_ws, size_t ws_size,
                              hipStream_t stream) {
    const float* x     = (const float*)d_in[0];
    const float* w     = (const float*)d_in[1];
    // d_in[2] = mask: tap positions are known analytically (3x3 dilated, centered at 32)
    const float* gamma = (const float*)d_in[3];
    const float* beta  = (const float*)d_in[4];
    float* out = (float*)d_out;

    float* ws    = (float*)d_ws;
    float* ybuf  = ws;                       // 6291456 floats
    float* psum  = ybuf + YELEMS;            // 96*64
    float* psq   = psum + COUT * 64;         // 96*64
    float* scale = psq + COUT * 64;          // 96
    float* shift = scale + COUT;             // 96

    conv_stats_kernel<<<768, 256, 0, stream>>>(x, w, ybuf, psum, psq);
    finalize_kernel<<<1, 128, 0, stream>>>(psum, psq, gamma, beta, scale, shift);
    bn_tanh_kernel<<<YELEMS / 1024, 256, 0, stream>>>(ybuf, scale, shift, out);
}

// Round 2
// 182.247 us; speedup vs baseline: 1.0016x; 1.0016x over previous
//
#include <hip/hip_runtime.h>
#include <math.h>

// Problem constants
#define BATCH 16
#define CIN 32
#define COUT 96
#define WH 64
#define IMG (WH*WH)              // 4096
#define NPIX (BATCH*IMG)         // 65536 per channel
#define YELEMS (BATCH*COUT*IMG)  // 6291456
#define NPART 128                // partials per channel: 16 b * 8 rowg

// ---------------------------------------------------------------------------
// conv + per-block stats
// grid = 16 b * 3 cfg * 4 chgroup * 8 rowgroup = 1536 blocks ; block 256
// Per block: 8 out-channels x 8 rows x 64 cols. Per thread: 2 rows x 1 col x 8 oc.
// x tile staged via global_load_lds (16B), double-buffered: prefetch c+1 after the
// barrier, compute c meanwhile. Weights read via uniform (scalar) loads -> SMEM pipe.
// ---------------------------------------------------------------------------
__global__ __launch_bounds__(256, 6) void conv_stats_kernel(
    const float* __restrict__ x, const float* __restrict__ w,
    float* __restrict__ y, float* __restrict__ psum, float* __restrict__ psq)
{
    int bid  = blockIdx.x;
    int rowg = bid & 7;            // 8 row groups of 8 rows
    int chg  = (bid >> 3) & 3;     // 4 out-channel groups of 8
    int rest = bid >> 5;           // 0..47
    int cfg  = rest % 3;
    int b    = rest / 3;
    int d    = cfg + 1;            // dilation 1,2,3 (block-uniform)
    int ocb  = cfg * 32 + chg * 8;
    int i0   = rowg * 8;

    int t  = threadIdx.x;
    int j  = t & 63;               // column
    int wv = t >> 6;               // wave 0..3
    int li = wv * 2;               // local output row base (0,2,4,6)

    // Two staging buffers of 16 rows x 64 cols (rows i0-3 .. i0+12; 14 needed, 16 staged
    // so all 256 threads do exactly one 16B global_load_lds: lane-contiguous LDS dest).
    __shared__ float xs[2][16 * 64];
    __shared__ float red[4][16];

    // staging addresses (constant over channel loop)
    int rr = t >> 4;               // 0..15  (row in tile)
    int cc = (t & 15) * 4;         // col (float4)
    int gi = (i0 - 3 + rr) & 63;   // circular source row
    const float* xsrc = x + (size_t)b * CIN * IMG + gi * 64 + cc;

    int jm = (j - d) & 63, jp = (j + d) & 63;

    float acc[2][8];
#pragma unroll
    for (int r = 0; r < 2; r++)
#pragma unroll
        for (int o = 0; o < 8; o++) acc[r][o] = 0.f;

    // uniform weight base: center tap of (ocb, c=0); tap offset = (du-1)*d*65 + (dv-1)*d
    const float* wb = w + ((size_t)ocb * CIN * 65 + 32) * 65 + 32;

    // prefetch channel 0 into buffer 0
    __builtin_amdgcn_global_load_lds(
        (const __attribute__((address_space(1))) void*)xsrc,
        (__attribute__((address_space(3))) void*)(&xs[0][t * 4]), 16, 0, 0);

    for (int c = 0; c < CIN; c++) {
        __syncthreads();  // drains vmcnt -> xs[c&1] ready; all readers of xs[(c+1)&1] done
        if (c + 1 < CIN) {
            __builtin_amdgcn_global_load_lds(
                (const __attribute__((address_space(1))) void*)(xsrc + (size_t)(c + 1) * IMG),
                (__attribute__((address_space(3))) void*)(&xs[(c + 1) & 1][t * 4]), 16, 0, 0);
        }
        const float* xbuf = &xs[c & 1][0];

        // gather the 18 x-values this thread needs (LDS, per-lane addresses)
        float xr[2][3][3];
#pragma unroll
        for (int r = 0; r < 2; r++) {
#pragma unroll
            for (int du = 0; du < 3; du++) {
                const float* row = xbuf + (li + r + 3 + (du - 1) * d) * 64;
                xr[r][du][0] = row[jm];
                xr[r][du][1] = row[j];
                xr[r][du][2] = row[jp];
            }
        }

        const float* wc = wb + (size_t)c * 65 * 65;
#pragma unroll
        for (int o = 0; o < 8; o++) {
            const float* wo = wc + (size_t)o * CIN * 65 * 65;
#pragma unroll
            for (int du = 0; du < 3; du++) {
#pragma unroll
                for (int dv = 0; dv < 3; dv++) {
                    // fully uniform index -> s_load (scalar pipe), SGPR operand in FMA
                    float wvv = wo[(du - 1) * d * 65 + (dv - 1) * d];
                    acc[0][o] = fmaf(xr[0][du][dv], wvv, acc[0][o]);
                    acc[1][o] = fmaf(xr[1][du][dv], wvv, acc[1][o]);
                }
            }
        }
    }

    // write y (coalesced over j) + per-thread sum/sumsq per channel
    float s[8], q[8];
#pragma unroll
    for (int o = 0; o < 8; o++) {
        size_t base = ((size_t)b * COUT + (ocb + o)) * IMG;
        float v0 = acc[0][o], v1 = acc[1][o];
        y[base + (size_t)(i0 + li) * WH + j]     = v0;
        y[base + (size_t)(i0 + li + 1) * WH + j] = v1;
        s[o] = v0 + v1;
        q[o] = fmaf(v0, v0, v1 * v1);
    }

    // wave butterfly reduce (64 lanes) -> per-wave 2-row totals
#pragma unroll
    for (int o = 0; o < 8; o++) {
        for (int m = 1; m < 64; m <<= 1) {
            s[o] += __shfl_xor(s[o], m, 64);
            q[o] += __shfl_xor(q[o], m, 64);
        }
    }
    int lane = t & 63;
    if (lane == 0) {
#pragma unroll
        for (int o = 0; o < 8; o++) { red[wv][o] = s[o]; red[wv][8 + o] = q[o]; }
    }
    __syncthreads();
    if (t < 16) {
        float v = red[0][t] + red[1][t] + red[2][t] + red[3][t];
        int o = t & 7;
        int slot = (ocb + o) * NPART + b * 8 + rowg;
        if (t < 8) psum[slot] = v; else psq[slot] = v;
    }
}

// ---------------------------------------------------------------------------
// fused finalize + BN + tanh
// grid = 16*96 = 1536 blocks, block 256; each block owns one (b,ch) 64x64 image.
// ---------------------------------------------------------------------------
__device__ __forceinline__ float fast_tanh(float xv) {
    float e = __expf(2.0f * xv);                       // v_exp_f32 path
    return fmaf(-2.0f, __builtin_amdgcn_rcpf(e + 1.0f), 1.0f);
}

__global__ __launch_bounds__(256) void bn_tanh_kernel(
    const float* __restrict__ ybuf, const float* __restrict__ psum,
    const float* __restrict__ psq, const float* __restrict__ gamma,
    const float* __restrict__ beta, float* __restrict__ out)
{
    __shared__ float part[4];
    __shared__ float sc[2];
    int t  = threadIdx.x;
    int ch = blockIdx.x % COUT;

    float s = 0.f, q = 0.f;
    if (t < NPART) { s = psum[ch * NPART + t]; q = psq[ch * NPART + t]; }
    for (int m = 1; m < 64; m <<= 1) {
        s += __shfl_xor(s, m, 64);
        q += __shfl_xor(q, m, 64);
    }
    if (t < NPART && (t & 63) == 0) { part[t >> 6] = s; part[2 + (t >> 6)] = q; }
    __syncthreads();
    if (t == 0) {
        const float inv_n = 1.0f / (float)NPIX;
        float S = part[0] + part[1], Q = part[2] + part[3];
        float mean = S * inv_n;
        float var  = Q * inv_n - mean * mean;
        float a    = gamma[ch] * rsqrtf(var + 1e-5f);
        sc[0] = a;
        sc[1] = beta[ch] - mean * a;
    }
    __syncthreads();

    float a = sc[0], bsh = sc[1];
    size_t base4 = (size_t)blockIdx.x * 1024;  // float4 units: 4096 floats per image
#pragma unroll
    for (int k = 0; k < 4; k++) {
        size_t e4 = base4 + k * 256 + t;
        float4 v = ((const float4*)ybuf)[e4];
        float4 r;
        r.x = fast_tanh(fmaf(v.x, a, bsh));
        r.y = fast_tanh(fmaf(v.y, a, bsh));
        r.z = fast_tanh(fmaf(v.z, a, bsh));
        r.w = fast_tanh(fmaf(v.w, a, bsh));
        ((float4*)out)[e4] = r;
    }
}

extern "C" void kernel_launch(void* const* d_in, const int* in_sizes, int n_in,
                              void* d_out, int out_size, void* d_ws, size_t ws_size,
                              hipStream_t stream) {
    const float* x     = (const float*)d_in[0];
    const float* w     = (const float*)d_in[1];
    // d_in[2] = mask: tap positions known analytically (3x3 dilated, centered at 32)
    const float* gamma = (const float*)d_in[3];
    const float* beta  = (const float*)d_in[4];
    float* out = (float*)d_out;

    float* ws    = (float*)d_ws;
    float* ybuf  = ws;                       // 6291456 floats
    float* psum  = ybuf + YELEMS;            // 96*128
    float* psq   = psum + COUT * NPART;      // 96*128

    conv_stats_kernel<<<1536, 256, 0, stream>>>(x, w, ybuf, psum, psq);
    bn_tanh_kernel<<<BATCH * COUT, 256, 0, stream>>>(ybuf, psum, psq, gamma, beta, out);
}

// Round 3
// 158.611 us; speedup vs baseline: 1.1508x; 1.1490x over previous
//
#include <hip/hip_runtime.h>
#include <math.h>

// Problem constants
#define BATCH 16
#define CIN 32
#define COUT 96
#define WH 64
#define IMG (WH*WH)              // 4096
#define NPIX (BATCH*IMG)         // 65536 per channel
#define YELEMS (BATCH*COUT*IMG)  // 6291456
#define NPART 128                // partials per channel: 16 b * 8 rowg
#define PWELEMS (12*CIN*72)      // 27648 packed weights

// ---------------------------------------------------------------------------
// weight pack: gather the 9 live taps per (oc, c) into a dense buffer
// pw[pb][c][o*9+tap], pb = cfg*4+chg (12 groups of 8 out-channels).
// Written into d_out (fully overwritten by bn_tanh afterwards).
// ---------------------------------------------------------------------------
__global__ __launch_bounds__(256) void pack_w_kernel(
    const float* __restrict__ w, float* __restrict__ pw)
{
    int e = blockIdx.x * 256 + threadIdx.x;
    if (e >= PWELEMS) return;
    int pb  = e / (CIN * 72);
    int rem = e % (CIN * 72);
    int c   = rem / 72;
    int k   = rem % 72;
    int o   = k / 9;
    int tap = k % 9;
    int cfg = pb >> 2, chg = pb & 3;
    int d   = cfg + 1;
    int oc  = cfg * 32 + chg * 8 + o;
    int du  = tap / 3, dv = tap % 3;
    pw[e] = w[(((size_t)oc * CIN + c) * 65 + (32 + (du - 1) * d)) * 65
              + (32 + (dv - 1) * d)];
}

// ---------------------------------------------------------------------------
// conv + per-block stats
// grid = 16 b * 3 cfg * 4 chgroup * 8 rowgroup = 1536 blocks ; block 256
// Per block: 8 out-channels x 8 rows x 64 cols. Per thread: 2 rows x 1 col x 8 oc.
// x tile staged via global_load_lds (16B), double-buffered. Weights from the
// dense packed buffer via contiguous scalar loads (288 B per channel, L2-hot).
// ---------------------------------------------------------------------------
__global__ __launch_bounds__(256, 4) void conv_stats_kernel(
    const float* __restrict__ x, const float* __restrict__ pw,
    float* __restrict__ y, float* __restrict__ psum, float* __restrict__ psq)
{
    int bid  = blockIdx.x;
    int rowg = bid & 7;            // 8 row groups of 8 rows
    int chg  = (bid >> 3) & 3;     // 4 out-channel groups of 8
    int rest = bid >> 5;           // 0..47
    int cfg  = rest % 3;
    int b    = rest / 3;
    int d    = cfg + 1;            // dilation 1,2,3 (block-uniform)
    int ocb  = cfg * 32 + chg * 8;
    int i0   = rowg * 8;

    int t  = threadIdx.x;
    int j  = t & 63;               // column
    int wv = t >> 6;               // wave 0..3
    int li = wv * 2;               // local output row base (0,2,4,6)

    __shared__ float xs[2][16 * 64];
    __shared__ float red[4][16];

    // staging addresses (constant over channel loop)
    int rr = t >> 4;               // 0..15  (row in tile)
    int cc = (t & 15) * 4;         // col (float4)
    int gi = (i0 - 3 + rr) & 63;   // circular source row
    const float* xsrc = x + (size_t)b * CIN * IMG + gi * 64 + cc;

    int jm = (j - d) & 63, jp = (j + d) & 63;

    float acc[2][8];
#pragma unroll
    for (int r = 0; r < 2; r++)
#pragma unroll
        for (int o = 0; o < 8; o++) acc[r][o] = 0.f;

    // dense packed weight slab for this block: 32 channels x 72 floats
    const float* wslab = pw + (size_t)(cfg * 4 + chg) * CIN * 72;

    // prefetch channel 0 into buffer 0
    __builtin_amdgcn_global_load_lds(
        (const __attribute__((address_space(1))) void*)xsrc,
        (__attribute__((address_space(3))) void*)(&xs[0][t * 4]), 16, 0, 0);

    for (int c = 0; c < CIN; c++) {
        __syncthreads();  // xs[c&1] ready; readers of xs[(c+1)&1] done
        if (c + 1 < CIN) {
            __builtin_amdgcn_global_load_lds(
                (const __attribute__((address_space(1))) void*)(xsrc + (size_t)(c + 1) * IMG),
                (__attribute__((address_space(3))) void*)(&xs[(c + 1) & 1][t * 4]), 16, 0, 0);
        }
        const float* xbuf = &xs[c & 1][0];

        // gather the 18 x-values this thread needs (LDS, per-lane addresses)
        float xr[2][3][3];
#pragma unroll
        for (int r = 0; r < 2; r++) {
#pragma unroll
            for (int du = 0; du < 3; du++) {
                const float* row = xbuf + (li + r + 3 + (du - 1) * d) * 64;
                xr[r][du][0] = row[jm];
                xr[r][du][1] = row[j];
                xr[r][du][2] = row[jp];
            }
        }

        // contiguous uniform weights: 72 floats -> wide s_loads, L2-hot
        const float* wc = wslab + c * 72;
#pragma unroll
        for (int o = 0; o < 8; o++) {
#pragma unroll
            for (int du = 0; du < 3; du++) {
#pragma unroll
                for (int dv = 0; dv < 3; dv++) {
                    float wvv = wc[o * 9 + du * 3 + dv];
                    acc[0][o] = fmaf(xr[0][du][dv], wvv, acc[0][o]);
                    acc[1][o] = fmaf(xr[1][du][dv], wvv, acc[1][o]);
                }
            }
        }
    }

    // write y (coalesced over j) + per-thread sum/sumsq per channel
    float s[8], q[8];
#pragma unroll
    for (int o = 0; o < 8; o++) {
        size_t base = ((size_t)b * COUT + (ocb + o)) * IMG;
        float v0 = acc[0][o], v1 = acc[1][o];
        y[base + (size_t)(i0 + li) * WH + j]     = v0;
        y[base + (size_t)(i0 + li + 1) * WH + j] = v1;
        s[o] = v0 + v1;
        q[o] = fmaf(v0, v0, v1 * v1);
    }

    // wave butterfly reduce (64 lanes)
#pragma unroll
    for (int o = 0; o < 8; o++) {
        for (int m = 1; m < 64; m <<= 1) {
            s[o] += __shfl_xor(s[o], m, 64);
            q[o] += __shfl_xor(q[o], m, 64);
        }
    }
    int lane = t & 63;
    if (lane == 0) {
#pragma unroll
        for (int o = 0; o < 8; o++) { red[wv][o] = s[o]; red[wv][8 + o] = q[o]; }
    }
    __syncthreads();
    if (t < 16) {
        float v = red[0][t] + red[1][t] + red[2][t] + red[3][t];
        int o = t & 7;
        int slot = (ocb + o) * NPART + b * 8 + rowg;
        if (t < 8) psum[slot] = v; else psq[slot] = v;
    }
}

// ---------------------------------------------------------------------------
// fused finalize + BN + tanh
// grid = 16*96 = 1536 blocks, block 256; each block owns one (b,ch) 64x64 image.
// ---------------------------------------------------------------------------
__device__ __forceinline__ float fast_tanh(float xv) {
    float e = __expf(2.0f * xv);
    return fmaf(-2.0f, __builtin_amdgcn_rcpf(e + 1.0f), 1.0f);
}

__global__ __launch_bounds__(256) void bn_tanh_kernel(
    const float* __restrict__ ybuf, const float* __restrict__ psum,
    const float* __restrict__ psq, const float* __restrict__ gamma,
    const float* __restrict__ beta, float* __restrict__ out)
{
    __shared__ float part[4];
    __shared__ float sc[2];
    int t  = threadIdx.x;
    int ch = blockIdx.x % COUT;

    float s = 0.f, q = 0.f;
    if (t < NPART) { s = psum[ch * NPART + t]; q = psq[ch * NPART + t]; }
    for (int m = 1; m < 64; m <<= 1) {
        s += __shfl_xor(s, m, 64);
        q += __shfl_xor(q, m, 64);
    }
    if (t < NPART && (t & 63) == 0) { part[t >> 6] = s; part[2 + (t >> 6)] = q; }
    __syncthreads();
    if (t == 0) {
        const float inv_n = 1.0f / (float)NPIX;
        float S = part[0] + part[1], Q = part[2] + part[3];
        float mean = S * inv_n;
        float var  = Q * inv_n - mean * mean;
        float a    = gamma[ch] * rsqrtf(var + 1e-5f);
        sc[0] = a;
        sc[1] = beta[ch] - mean * a;
    }
    __syncthreads();

    float a = sc[0], bsh = sc[1];
    size_t base4 = (size_t)blockIdx.x * 1024;  // float4 units
#pragma unroll
    for (int k = 0; k < 4; k++) {
        size_t e4 = base4 + k * 256 + t;
        float4 v = ((const float4*)ybuf)[e4];
        float4 r;
        r.x = fast_tanh(fmaf(v.x, a, bsh));
        r.y = fast_tanh(fmaf(v.y, a, bsh));
        r.z = fast_tanh(fmaf(v.z, a, bsh));
        r.w = fast_tanh(fmaf(v.w, a, bsh));
        ((float4*)out)[e4] = r;
    }
}

extern "C" void kernel_launch(void* const* d_in, const int* in_sizes, int n_in,
                              void* d_out, int out_size, void* d_ws, size_t ws_size,
                              hipStream_t stream) {
    const float* x     = (const float*)d_in[0];
    const float* w     = (const float*)d_in[1];
    // d_in[2] = mask: tap positions known analytically (3x3 dilated, centered at 32)
    const float* gamma = (const float*)d_in[3];
    const float* beta  = (const float*)d_in[4];
    float* out = (float*)d_out;

    float* ws    = (float*)d_ws;
    float* ybuf  = ws;                       // 6291456 floats
    float* psum  = ybuf + YELEMS;            // 96*128
    float* psq   = psum + COUT * NPART;      // 96*128

    // packed weights live in d_out's front 110 KB; conv reads them while
    // writing only ybuf (d_ws); bn_tanh later overwrites all of d_out.
    float* pwbuf = out;

    pack_w_kernel<<<(PWELEMS + 255) / 256, 256, 0, stream>>>(w, pwbuf);
    conv_stats_kernel<<<1536, 256, 0, stream>>>(x, pwbuf, ybuf, psum, psq);
    bn_tanh_kernel<<<BATCH * COUT, 256, 0, stream>>>(ybuf, psum, psq, gamma, beta, out);
}